// Round 10
// baseline (370.185 us; speedup 1.0000x reference)
//
#include <hip/hip_runtime.h>

typedef __attribute__((ext_vector_type(8))) _Float16 half8;
typedef __attribute__((ext_vector_type(4))) float f32x4;
typedef __attribute__((ext_vector_type(2))) float f32x2;

#define TSTEPS 50
#define HOR    50
#define RSC    2048.0f          // residual scale (2^11)
#define RSCI   (1.0f/2048.0f)

__device__ __forceinline__ float frcp(float x) { return __builtin_amdgcn_rcpf(x); }
__device__ __forceinline__ float sigmoidf(float x) { return frcp(1.f + __expf(-x)); }
__device__ __forceinline__ float tanh_fast(float x) {
  float ax = fabsf(x);
  float e  = __expf(-2.f * ax);
  float r  = (1.f - e) * frcp(1.f + e);
  return copysignf(r, x);
}
union HU { _Float16 h; unsigned short u; };
__device__ __forceinline__ unsigned short f2h_u(float x) { HU t; t.h = (_Float16)x; return t.u; }
__device__ __forceinline__ float h2f_u(unsigned short u) { HU t; t.u = u; return (float)t.h; }

__global__ __launch_bounds__(256, 2)
void traj_lstm_h16(const float* __restrict__ hist,   // (B, 50, 2)
                   const float* __restrict__ W_ih,   // (256, 2)
                   const float* __restrict__ W_hh,   // (256, 64)
                   const float* __restrict__ b_ih,   // (256)
                   const float* __restrict__ b_hh,   // (256)
                   const float* __restrict__ W_dec,  // (2, 64)
                   const float* __restrict__ b_dec,  // (2)
                   float* __restrict__ out)          // (B, 50, 2)
{
  // h exchange: fp16 value + fp16 scaled-residual, double-buffered
  __shared__ unsigned short hsh0[2][32][72];   // 9.2 KB (row 144 B, 16B-mult)
  __shared__ unsigned short hsh1[2][32][72];   // 9.2 KB
  __shared__ float wdl[2][64];                 // W_dec rows
  __shared__ float bdl2[2];

  const int tid  = threadIdx.x;
  const int q    = tid >> 6;    // hidden quarter: j in [16q, 16q+16)
  const int lane = tid & 63;
  const int col  = lane & 15;
  const int g    = lane >> 4;
  const int batch0 = blockIdx.x * 32;

  if (tid < 128) wdl[tid >> 6][tid & 63] = W_dec[tid];
  if (tid < 2)   bdl2[tid] = b_dec[tid];
  for (int idx = tid; idx < 2 * 32 * 72; idx += 256) {
    ((unsigned short*)hsh0)[idx] = 0;   // fp16 zero
    ((unsigned short*)hsh1)[idx] = 0;
  }

  // ---- W_hh fragments: fp16 value + fp16 scaled residual, resident (64 VGPR)
  // tile gt: gate rows gt*64 + 16q + col; B[k][n]: n=col, k = kq*32 + 8g + e
  half8 wb0[4][2], wb1[4][2];
  #pragma unroll
  for (int gt = 0; gt < 4; ++gt) {
    const int row = gt * 64 + q * 16 + col;
    #pragma unroll
    for (int kq = 0; kq < 2; ++kq) {
      #pragma unroll
      for (int e = 0; e < 8; ++e) {
        float f = W_hh[row * 64 + kq * 32 + g * 8 + e];
        _Float16 h0 = (_Float16)f;
        wb0[gt][kq][e] = h0;
        wb1[gt][kq][e] = (_Float16)((f - (float)h0) * RSC);
      }
    }
  }

  // ---- per-cell constants resident (12 VGPR): gate row gt*64 + 16q + col ----
  float bias[4], wx[4], wy[4];
  #pragma unroll
  for (int gt = 0; gt < 4; ++gt) {
    const int row = gt * 64 + q * 16 + col;
    bias[gt] = b_ih[row] + b_hh[row];
    wx[gt]   = W_ih[row * 2];
    wy[gt]   = W_ih[row * 2 + 1];
  }

  // lane's batches: bg*16 + 4g + r  (bg = batch-group 0/1)
  const float* pb[2];
  pb[0] = hist + (size_t)(batch0 + 4 * g) * 100;
  pb[1] = hist + (size_t)(batch0 + 16 + 4 * g) * 100;

  float cst[2][4] = {{0.f,0.f,0.f,0.f},{0.f,0.f,0.f,0.f}};
  float p0[2] = {0.f, 0.f}, p1[2] = {0.f, 0.f};

  __syncthreads();

  for (int s = 0; s < TSTEPS + HOR; ++s) {
    const int par = s & 1;

    // ---- A fragments: direct fp16 value/residual reads ----
    half8 a0[2][2], a1[2][2];
    #pragma unroll
    for (int bg = 0; bg < 2; ++bg)
      #pragma unroll
      for (int kq = 0; kq < 2; ++kq) {
        a0[bg][kq] = *(const half8*)&hsh0[par][bg * 16 + col][kq * 32 + g * 8];
        a1[bg][kq] = *(const half8*)&hsh1[par][bg * 16 + col][kq * 32 + g * 8];
      }

    // ---- x for this step (fp32 path, exact) ----
    float x0[2][4], x1[2][4];
    if (s <= TSTEPS) {
      #pragma unroll
      for (int bg = 0; bg < 2; ++bg)
        #pragma unroll
        for (int r = 0; r < 4; ++r) {
          f32x2 xv = *(const f32x2*)(pb[bg] + r * 100);
          x0[bg][r] = xv.x; x1[bg][r] = xv.y;
        }
      if (s < TSTEPS - 1) { pb[0] += 2; pb[1] += 2; }
    } else {
      #pragma unroll
      for (int bg = 0; bg < 2; ++bg)
        #pragma unroll
        for (int r = 0; r < 4; ++r) {
          x0[bg][r] = __shfl(p0[bg], 4 * g + r);
          x1[bg][r] = __shfl(p1[bg], 4 * g + r);
        }
    }

    // ---- 48 MFMAs: accH (value*value) + accL (cross terms, scaled 2^11) ----
    f32x4 gatev[4][2];
    #pragma unroll
    for (int gt = 0; gt < 4; ++gt)
      #pragma unroll
      for (int bg = 0; bg < 2; ++bg) {
        f32x4 aH = {0.f,0.f,0.f,0.f};
        f32x4 aL = {0.f,0.f,0.f,0.f};
        aH = __builtin_amdgcn_mfma_f32_16x16x32_f16(a0[bg][0], wb0[gt][0], aH, 0, 0, 0);
        aH = __builtin_amdgcn_mfma_f32_16x16x32_f16(a0[bg][1], wb0[gt][1], aH, 0, 0, 0);
        aL = __builtin_amdgcn_mfma_f32_16x16x32_f16(a1[bg][0], wb0[gt][0], aL, 0, 0, 0);
        aL = __builtin_amdgcn_mfma_f32_16x16x32_f16(a1[bg][1], wb0[gt][1], aL, 0, 0, 0);
        aL = __builtin_amdgcn_mfma_f32_16x16x32_f16(a0[bg][0], wb1[gt][0], aL, 0, 0, 0);
        aL = __builtin_amdgcn_mfma_f32_16x16x32_f16(a0[bg][1], wb1[gt][1], aL, 0, 0, 0);
        #pragma unroll
        for (int r = 0; r < 4; ++r) gatev[gt][bg][r] = fmaf(aL[r], RSCI, aH[r]);
      }

    // ---- LSTM cell: batch bg*16+4g+r, hidden j = 16q+col ----
    #pragma unroll
    for (int bg = 0; bg < 2; ++bg)
      #pragma unroll
      for (int r = 0; r < 4; ++r) {
        float gi = gatev[0][bg][r] + bias[0] + x0[bg][r] * wx[0] + x1[bg][r] * wy[0];
        float gf = gatev[1][bg][r] + bias[1] + x0[bg][r] * wx[1] + x1[bg][r] * wy[1];
        float gg = gatev[2][bg][r] + bias[2] + x0[bg][r] * wx[2] + x1[bg][r] * wy[2];
        float go = gatev[3][bg][r] + bias[3] + x0[bg][r] * wx[3] + x1[bg][r] * wy[3];
        float si = sigmoidf(gi);
        float sf = sigmoidf(gf);
        float tg = tanh_fast(gg);
        float so = sigmoidf(go);
        float cn = fmaf(sf, cst[bg][r], si * tg);
        cst[bg][r] = cn;
        float hv = so * tanh_fast(cn);
        _Float16 h0 = (_Float16)hv;
        HU t0; t0.h = h0;
        unsigned short h1u = f2h_u((hv - (float)h0) * RSC);
        const int row = bg * 16 + 4 * g + r;
        hsh0[par ^ 1][row][q * 16 + col] = t0.u;
        hsh1[par ^ 1][row][q * 16 + col] = h1u;
      }
    __syncthreads();   // the only barrier per step

    // ---- decoder: every wave computes both features (barrier-free) ----
    if (s >= TSTEPS) {
      #pragma unroll
      for (int bg = 0; bg < 2; ++bg) {
        const unsigned short* H0 = &hsh0[par ^ 1][bg * 16 + col][g * 16];
        const unsigned short* H1 = &hsh1[par ^ 1][bg * 16 + col][g * 16];
        half8 v0a = *(const half8*)&H0[0], v0b = *(const half8*)&H0[8];
        half8 v1a = *(const half8*)&H1[0], v1b = *(const half8*)&H1[8];
        float s0 = 0.f, s1 = 0.f;
        #pragma unroll
        for (int e = 0; e < 8; ++e) {
          float hva = fmaf(RSCI, (float)v1a[e], (float)v0a[e]);
          float hvb = fmaf(RSCI, (float)v1b[e], (float)v0b[e]);
          s0 = fmaf(hva, wdl[0][g * 16 + e], s0);
          s0 = fmaf(hvb, wdl[0][g * 16 + 8 + e], s0);
          s1 = fmaf(hva, wdl[1][g * 16 + e], s1);
          s1 = fmaf(hvb, wdl[1][g * 16 + 8 + e], s1);
        }
        s0 += __shfl_xor(s0, 16); s0 += __shfl_xor(s0, 32);
        s1 += __shfl_xor(s1, 16); s1 += __shfl_xor(s1, 32);
        p0[bg] = s0 + bdl2[0];
        p1[bg] = s1 + bdl2[1];   // lane L: features of batch bg*16 + (L&15)
      }
      if (q == 0 && g == 0) {
        f32x2 oa = { p0[0], p1[0] };
        f32x2 ob = { p0[1], p1[1] };
        *(f32x2*)&out[(size_t)(batch0 + col) * 100 + (size_t)(s - TSTEPS) * 2] = oa;
        *(f32x2*)&out[(size_t)(batch0 + 16 + col) * 100 + (size_t)(s - TSTEPS) * 2] = ob;
      }
    }
  }
}

extern "C" void kernel_launch(void* const* d_in, const int* in_sizes, int n_in,
                              void* d_out, int out_size, void* d_ws, size_t ws_size,
                              hipStream_t stream) {
  (void)in_sizes; (void)n_in; (void)ws_size; (void)d_ws; (void)out_size;
  const float* hist  = (const float*)d_in[0];
  const float* W_ih  = (const float*)d_in[1];
  const float* W_hh  = (const float*)d_in[2];
  const float* b_ih  = (const float*)d_in[3];
  const float* b_hh  = (const float*)d_in[4];
  const float* W_dec = (const float*)d_in[5];
  const float* b_dec = (const float*)d_in[6];
  float* out = (float*)d_out;

  dim3 grid(16384 / 32);   // 512 blocks: 32 batches, 4 quarter-split waves
  dim3 block(256);
  traj_lstm_h16<<<grid, block, 0, stream>>>(hist, W_ih, W_hh, b_ih, b_hh,
                                            W_dec, b_dec, out);
}

// Round 11
// 338.337 us; speedup vs baseline: 1.0941x; 1.0941x over previous
//
#include <hip/hip_runtime.h>

typedef __attribute__((ext_vector_type(8))) _Float16 half8;
typedef __attribute__((ext_vector_type(4))) float f32x4;
typedef __attribute__((ext_vector_type(2))) float f32x2;

#define TSTEPS 50
#define HOR    50
#define RSC    2048.0f          // residual scale (2^11)
#define RSCI   (1.0f/2048.0f)

__device__ __forceinline__ float frcp(float x) { return __builtin_amdgcn_rcpf(x); }
__device__ __forceinline__ float sigmoidf(float x) { return frcp(1.f + __expf(-x)); }
__device__ __forceinline__ float tanh_fast(float x) {
  // tanh(x) = 2/(1+e^{-2x}) - 1 ; large -x: e=inf -> rcp=0 -> -1 (no NaN)
  float e = __expf(-2.f * x);
  return fmaf(2.f, frcp(1.f + e), -1.f);
}
union HU { _Float16 h; unsigned short u; };
__device__ __forceinline__ unsigned short f2h_u(float x) { HU t; t.h = (_Float16)x; return t.u; }

__global__ __launch_bounds__(256, 4)
void traj_lstm_r11(const float* __restrict__ hist,   // (B, 50, 2)
                   const float* __restrict__ W_ih,   // (256, 2)
                   const float* __restrict__ W_hh,   // (256, 64)
                   const float* __restrict__ b_ih,   // (256)
                   const float* __restrict__ b_hh,   // (256)
                   const float* __restrict__ W_dec,  // (2, 64)
                   const float* __restrict__ b_dec,  // (2)
                   float* __restrict__ out)          // (B, 50, 2)
{
  // h exchange: fp16 value + fp16 scaled-residual, double-buffered
  __shared__ unsigned short hsh0[2][16][72];   // 4.6 KB
  __shared__ unsigned short hsh1[2][16][72];   // 4.6 KB
  __shared__ f32x4 cwl[256];                   // 4 KB: {bias, wx, wy, 0} per gate row
  __shared__ float wdl[2][64];                 // W_dec rows
  __shared__ float bdl[2];

  const int tid  = threadIdx.x;
  const int q    = tid >> 6;    // hidden quarter: j in [16q, 16q+16)
  const int lane = tid & 63;
  const int col  = lane & 15;
  const int g    = lane >> 4;
  const int batch0 = blockIdx.x * 16;

  // ---- one-time staging ----
  {
    const int row = tid;   // 256 threads, one gate row each
    f32x4 cv;
    cv.x = b_ih[row] + b_hh[row];
    cv.y = W_ih[2 * row];
    cv.z = W_ih[2 * row + 1];
    cv.w = 0.f;
    cwl[row] = cv;
  }
  if (tid < 128) wdl[tid >> 6][tid & 63] = W_dec[tid];
  if (tid < 2)   bdl[tid] = b_dec[tid];
  for (int idx = tid; idx < 2 * 16 * 72; idx += 256) {
    ((unsigned short*)hsh0)[idx] = 0;   // fp16 zero
    ((unsigned short*)hsh1)[idx] = 0;
  }

  // ---- W_hh fragments: fp16 value + fp16 scaled residual, resident (64 VGPR)
  // tile gt: gate rows gt*64 + 16q + col; B[k][n]: n=col, k = kq*32 + 8g + e
  half8 wb0[4][2], wb1[4][2];
  #pragma unroll
  for (int gt = 0; gt < 4; ++gt) {
    const int row = gt * 64 + q * 16 + col;
    #pragma unroll
    for (int kq = 0; kq < 2; ++kq) {
      #pragma unroll
      for (int e = 0; e < 8; ++e) {
        float f = W_hh[row * 64 + kq * 32 + g * 8 + e];
        _Float16 h0 = (_Float16)f;
        wb0[gt][kq][e] = h0;
        wb1[gt][kq][e] = (_Float16)((f - (float)h0) * RSC);
      }
    }
  }

  float cst[4] = {0.f, 0.f, 0.f, 0.f};
  float p0 = 0.f, p1 = 0.f;   // decode feedback (batch = this lane's col)

  __syncthreads();

  for (int s = 0; s < TSTEPS + HOR; ++s) {
    const int par = s & 1;

    // ---- A fragments: direct fp16 value/residual reads ----
    half8 a0[2], a1[2];
    #pragma unroll
    for (int kq = 0; kq < 2; ++kq) {
      a0[kq] = *(const half8*)&hsh0[par][col][kq * 32 + g * 8];
      a1[kq] = *(const half8*)&hsh1[par][col][kq * 32 + g * 8];
    }

    // ---- x for this step (fp32 path, exact) ----
    float x0[4], x1[4];
    if (s <= TSTEPS) {
      const int ss = (s < TSTEPS) ? s : (TSTEPS - 1);
      #pragma unroll
      for (int r = 0; r < 4; ++r) {
        f32x2 xv = *(const f32x2*)&hist[(size_t)(batch0 + 4 * g + r) * 100 + ss * 2];
        x0[r] = xv.x; x1[r] = xv.y;
      }
    } else {
      #pragma unroll
      for (int r = 0; r < 4; ++r) {   // batch 4g+r's features live in lane 4g+r
        x0[r] = __shfl(p0, 4 * g + r);
        x1[r] = __shfl(p1, 4 * g + r);
      }
    }

    // ---- 24 MFMAs: accH (value*value) + accL (cross terms, scaled 2^11) ----
    f32x4 gatev[4];
    #pragma unroll
    for (int gt = 0; gt < 4; ++gt) {
      f32x4 aH = {0.f,0.f,0.f,0.f};
      f32x4 aL = {0.f,0.f,0.f,0.f};
      aH = __builtin_amdgcn_mfma_f32_16x16x32_f16(a0[0], wb0[gt][0], aH, 0, 0, 0);
      aH = __builtin_amdgcn_mfma_f32_16x16x32_f16(a0[1], wb0[gt][1], aH, 0, 0, 0);
      aL = __builtin_amdgcn_mfma_f32_16x16x32_f16(a1[0], wb0[gt][0], aL, 0, 0, 0);
      aL = __builtin_amdgcn_mfma_f32_16x16x32_f16(a1[1], wb0[gt][1], aL, 0, 0, 0);
      aL = __builtin_amdgcn_mfma_f32_16x16x32_f16(a0[0], wb1[gt][0], aL, 0, 0, 0);
      aL = __builtin_amdgcn_mfma_f32_16x16x32_f16(a0[1], wb1[gt][1], aL, 0, 0, 0);
      #pragma unroll
      for (int r = 0; r < 4; ++r) gatev[gt][r] = fmaf(aL[r], RSCI, aH[r]);
    }

    // ---- per-cell constants from LDS (A-frags dead -> registers reused) ----
    f32x4 cv[4];
    #pragma unroll
    for (int gt = 0; gt < 4; ++gt) cv[gt] = cwl[gt * 64 + q * 16 + col];

    // ---- LSTM cell: batch 4g+r, hidden j = 16q+col ----
    #pragma unroll
    for (int r = 0; r < 4; ++r) {
      float gi = gatev[0][r] + cv[0].x + x0[r] * cv[0].y + x1[r] * cv[0].z;
      float gf = gatev[1][r] + cv[1].x + x0[r] * cv[1].y + x1[r] * cv[1].z;
      float gg = gatev[2][r] + cv[2].x + x0[r] * cv[2].y + x1[r] * cv[2].z;
      float go = gatev[3][r] + cv[3].x + x0[r] * cv[3].y + x1[r] * cv[3].z;
      float si = sigmoidf(gi);
      float sf = sigmoidf(gf);
      float tg = tanh_fast(gg);
      float so = sigmoidf(go);
      float cn = fmaf(sf, cst[r], si * tg);
      cst[r] = cn;
      float hv = so * tanh_fast(cn);
      _Float16 h0 = (_Float16)hv;
      HU t0; t0.h = h0;
      unsigned short h1u = f2h_u((hv - (float)h0) * RSC);
      hsh0[par ^ 1][4 * g + r][q * 16 + col] = t0.u;
      hsh1[par ^ 1][4 * g + r][q * 16 + col] = h1u;
    }
    __syncthreads();   // the only barrier per step

    // ---- decoder: every wave computes both features (barrier-free) ----
    if (s >= TSTEPS) {
      const unsigned short* H0 = &hsh0[par ^ 1][col][g * 16];
      const unsigned short* H1 = &hsh1[par ^ 1][col][g * 16];
      half8 v0a = *(const half8*)&H0[0], v0b = *(const half8*)&H0[8];
      half8 v1a = *(const half8*)&H1[0], v1b = *(const half8*)&H1[8];
      float s0 = 0.f, s1 = 0.f;
      #pragma unroll
      for (int e = 0; e < 8; ++e) {
        float hva = fmaf(RSCI, (float)v1a[e], (float)v0a[e]);
        float hvb = fmaf(RSCI, (float)v1b[e], (float)v0b[e]);
        s0 = fmaf(hva, wdl[0][g * 16 + e], s0);
        s0 = fmaf(hvb, wdl[0][g * 16 + 8 + e], s0);
        s1 = fmaf(hva, wdl[1][g * 16 + e], s1);
        s1 = fmaf(hvb, wdl[1][g * 16 + 8 + e], s1);
      }
      s0 += __shfl_xor(s0, 16); s0 += __shfl_xor(s0, 32);
      s1 += __shfl_xor(s1, 16); s1 += __shfl_xor(s1, 32);
      p0 = s0 + bdl[0];
      p1 = s1 + bdl[1];        // lane L: features of batch (L & 15)

      if (q == 0 && g == 0) {
        f32x2 o2 = { p0, p1 };
        *(f32x2*)&out[(size_t)(batch0 + col) * 100 + (size_t)(s - TSTEPS) * 2] = o2;
      }
    }
  }
}

extern "C" void kernel_launch(void* const* d_in, const int* in_sizes, int n_in,
                              void* d_out, int out_size, void* d_ws, size_t ws_size,
                              hipStream_t stream) {
  (void)in_sizes; (void)n_in; (void)ws_size; (void)d_ws; (void)out_size;
  const float* hist  = (const float*)d_in[0];
  const float* W_ih  = (const float*)d_in[1];
  const float* W_hh  = (const float*)d_in[2];
  const float* b_ih  = (const float*)d_in[3];
  const float* b_hh  = (const float*)d_in[4];
  const float* W_dec = (const float*)d_in[5];
  const float* b_dec = (const float*)d_in[6];
  float* out = (float*)d_out;

  dim3 grid(16384 / 16);   // 1024 blocks: 16 batches, 4 quarter-split waves
  dim3 block(256);
  traj_lstm_r11<<<grid, block, 0, stream>>>(hist, W_ih, W_hh, b_ih, b_hh,
                                            W_dec, b_dec, out);
}